// Round 13
// baseline (306.273 us; speedup 1.0000x reference)
//
#include <hip/hip_runtime.h>
#include <float.h>

#define EPS 1e-5f
#define FMA4(A_, W_, T_) { (A_).x += (W_)*(T_).x; (A_).y += (W_)*(T_).y; (A_).z += (W_)*(T_).z; (A_).w += (W_)*(T_).w; }

// ---------------- K1: max over last dim: (32,512,2048) -> (32*512) ----------------
__global__ __launch_bounds__(256) void k1_maxpool(const float* __restrict__ gf, float* __restrict__ gfeat) {
    int row = blockIdx.x * 4 + (threadIdx.x >> 6);   // one wave per row
    int lane = threadIdx.x & 63;
    const float4* p = (const float4*)(gf + (size_t)row * 2048);
    float m = -FLT_MAX;
#pragma unroll
    for (int w = 0; w < 8; ++w) {
        float4 v = p[lane + (w << 6)];
        m = fmaxf(m, fmaxf(fmaxf(v.x, v.y), fmaxf(v.z, v.w)));
    }
#pragma unroll
    for (int off = 32; off >= 1; off >>= 1) m = fmaxf(m, __shfl_xor(m, off));
    if (lane == 0) gfeat[row] = m;
}

// ---------------- K2: tok = relu(bn(gfeat @ token_w^T + token_b)) : (32,65536) ----------------
__global__ __launch_bounds__(256) void k2_token(
    const float* __restrict__ gfeat, const float* __restrict__ tw, const float* __restrict__ tbias,
    const float* __restrict__ bg, const float* __restrict__ bb,
    const float* __restrict__ bm, const float* __restrict__ bv,
    float* __restrict__ tok) {
    __shared__ __align__(16) float wl[128 * 33];
    __shared__ __align__(16) float gl[32 * 36];
    int tid = threadIdx.x;
    int t0 = blockIdx.x * 128;
    int tx = tid & 7, ty = tid >> 3;
    float4 acc[4];
#pragma unroll
    for (int i = 0; i < 4; ++i) acc[i] = make_float4(0.f, 0.f, 0.f, 0.f);
    for (int k0 = 0; k0 < 512; k0 += 32) {
        if (k0) __syncthreads();
        {
            int r = tid >> 1, h = tid & 1;
            const float* src = tw + (size_t)(t0 + r) * 512 + k0 + h * 16;
            float* dst = wl + r * 33 + h * 16;
#pragma unroll
            for (int q = 0; q < 4; ++q) {
                float4 x = *(const float4*)(src + q * 4);
                dst[q*4+0] = x.x; dst[q*4+1] = x.y; dst[q*4+2] = x.z; dst[q*4+3] = x.w;
            }
            int bq = tid >> 3, kq = tid & 7;
            float4 gx = *(const float4*)(gfeat + bq * 512 + k0 + kq * 4);
            gl[(kq*4+0)*36 + bq] = gx.x;
            gl[(kq*4+1)*36 + bq] = gx.y;
            gl[(kq*4+2)*36 + bq] = gx.z;
            gl[(kq*4+3)*36 + bq] = gx.w;
        }
        __syncthreads();
#pragma unroll
        for (int kk = 0; kk < 32; ++kk) {
            float4 g4 = *(const float4*)(gl + kk * 36 + tx * 4);
#pragma unroll
            for (int i = 0; i < 4; ++i) {
                float a = wl[(ty * 4 + i) * 33 + kk];
                FMA4(acc[i], a, g4);
            }
        }
    }
#pragma unroll
    for (int i = 0; i < 4; ++i) {
        int t = t0 + ty * 4 + i;
        float scale = bg[t] * rsqrtf(bv[t] + EPS);
        float sh = (tbias[t] - bm[t]) * scale + bb[t];
        tok[(size_t)(tx*4+0) * 65536 + t] = fmaxf(acc[i].x * scale + sh, 0.f);
        tok[(size_t)(tx*4+1) * 65536 + t] = fmaxf(acc[i].y * scale + sh, 0.f);
        tok[(size_t)(tx*4+2) * 65536 + t] = fmaxf(acc[i].z * scale + sh, 0.f);
        tok[(size_t)(tx*4+3) * 65536 + t] = fmaxf(acc[i].w * scale + sh, 0.f);
    }
}

// ---------------- K3: k,v projections -> padded [b][n][128] buffers ----------------
__global__ __launch_bounds__(256) void k3_kv(
    const float* __restrict__ tok,
    const float* __restrict__ kw, const float* __restrict__ vw,
    const float* __restrict__ kg, const float* __restrict__ kb, const float* __restrict__ km, const float* __restrict__ kvv,
    const float* __restrict__ vg, const float* __restrict__ vb, const float* __restrict__ vm, const float* __restrict__ vvv,
    float* __restrict__ kbuf, float* __restrict__ vbuf) {
    __shared__ __align__(16) float tokt[64 * 68];    // [n][c]
    int tid = threadIdx.x;
    int b = blockIdx.y;
    int n0 = blockIdx.x << 6;
    for (int i = tid; i < 1024; i += 256) {
        int c = i >> 4, q4 = i & 15;
        float4 x = *(const float4*)(tok + (size_t)b * 65536 + c * 1024 + n0 + q4 * 4);
        tokt[(q4*4+0)*68 + c] = x.x;
        tokt[(q4*4+1)*68 + c] = x.y;
        tokt[(q4*4+2)*68 + c] = x.z;
        tokt[(q4*4+3)*68 + c] = x.w;
    }
    int o = tid & 127;
    bool valid = (o < 122);
    float kscl = 0.f, kshf = 0.f, vscl = 0.f, vshf = 0.f;
    if (valid) {
        float s = kg[o] * rsqrtf(kvv[o] + EPS);
        kscl = s; kshf = kb[o] - km[o] * s;
        s = vg[o] * rsqrtf(vvv[o] + EPS);
        vscl = s; vshf = vb[o] - vm[o] * s;
    }
    float4 kwreg[16], vwreg[16];
    {
        const float* kwr = kw + o * 64;
        const float* vwr = vw + o * 64;
#pragma unroll
        for (int c4 = 0; c4 < 16; ++c4) {
            kwreg[c4] = valid ? *(const float4*)(kwr + c4 * 4) : make_float4(0.f,0.f,0.f,0.f);
            vwreg[c4] = valid ? *(const float4*)(vwr + c4 * 4) : make_float4(0.f,0.f,0.f,0.f);
        }
    }
    __syncthreads();
    for (int nn = (tid >> 7); nn < 64; nn += 2) {
        const float* t = tokt + nn * 68;
        float sk = 0.f, sv = 0.f;
#pragma unroll
        for (int c4 = 0; c4 < 16; ++c4) {
            float4 tv = *(const float4*)(t + c4 * 4);
            sk += kwreg[c4].x*tv.x + kwreg[c4].y*tv.y + kwreg[c4].z*tv.z + kwreg[c4].w*tv.w;
            sv += vwreg[c4].x*tv.x + vwreg[c4].y*tv.y + vwreg[c4].z*tv.z + vwreg[c4].w*tv.w;
        }
        size_t base = ((size_t)b * 1024 + n0 + nn) * 128 + o;
        kbuf[base] = fmaxf(sk * kscl + kshf, 0.f);
        vbuf[base] = fmaxf(sv * vscl + vshf, 0.f);
    }
}

// ---------------- K3q: q projection -> padded [b][n][128] ----------------
__global__ __launch_bounds__(256) void k3_q(
    const float* __restrict__ tok,
    const float* __restrict__ qw,
    const float* __restrict__ qg, const float* __restrict__ qb, const float* __restrict__ qm, const float* __restrict__ qv,
    float* __restrict__ qbuf) {
    __shared__ __align__(16) float tokt[64 * 68];
    int tid = threadIdx.x;
    int b = blockIdx.y;
    int n0 = blockIdx.x << 6;
    for (int i = tid; i < 1024; i += 256) {
        int c = i >> 4, q4 = i & 15;
        float4 x = *(const float4*)(tok + (size_t)b * 65536 + c * 1024 + n0 + q4 * 4);
        tokt[(q4*4+0)*68 + c] = x.x;
        tokt[(q4*4+1)*68 + c] = x.y;
        tokt[(q4*4+2)*68 + c] = x.z;
        tokt[(q4*4+3)*68 + c] = x.w;
    }
    int o = tid & 127;
    bool valid = (o < 122);
    float scl = 0.f, shf = 0.f;
    if (valid) {
        float s = qg[o] * rsqrtf(qv[o] + EPS);
        scl = s; shf = qb[o] - qm[o] * s;
    }
    float4 wreg[16];
    {
        const float* wr = qw + o * 64;
#pragma unroll
        for (int c4 = 0; c4 < 16; ++c4)
            wreg[c4] = valid ? *(const float4*)(wr + c4 * 4) : make_float4(0.f,0.f,0.f,0.f);
    }
    __syncthreads();
    for (int nn = (tid >> 7); nn < 64; nn += 2) {
        const float* t = tokt + nn * 68;
        float s = 0.f;
#pragma unroll
        for (int c4 = 0; c4 < 16; ++c4) {
            float4 tv = *(const float4*)(t + c4 * 4);
            s += wreg[c4].x*tv.x + wreg[c4].y*tv.y + wreg[c4].z*tv.z + wreg[c4].w*tv.w;
        }
        qbuf[((size_t)b * 1024 + n0 + nn) * 128 + o] = fmaxf(s * scl + shf, 0.f);
    }
}

// ---------------- K4: S partials — pure outer-product GEMM over n ----------------
__global__ __launch_bounds__(256) void k4_s(
    const float* __restrict__ kbuf, const float* __restrict__ vbuf,
    float* __restrict__ sp) {
    __shared__ __align__(16) float kl[32 * 128];
    __shared__ __align__(16) float vl[32 * 128];
    int tid = threadIdx.x;
    int b = blockIdx.y, ns = blockIdx.x;
    int tx = tid & 15, ty = tid >> 4;
    float acc[8][8];
#pragma unroll
    for (int i = 0; i < 8; ++i)
#pragma unroll
        for (int j = 0; j < 8; ++j) acc[i][j] = 0.f;
    for (int chunk = 0; chunk < 2; ++chunk) {
        int nb = (ns << 6) + (chunk << 5);
        if (chunk) __syncthreads();
        for (int i = tid; i < 1024; i += 256) {
            int n = i >> 5, q = i & 31;
            size_t src = ((size_t)b * 1024 + nb + n) * 128 + q * 4;
            *(float4*)(kl + n * 128 + q * 4) = *(const float4*)(kbuf + src);
            *(float4*)(vl + n * 128 + q * 4) = *(const float4*)(vbuf + src);
        }
        __syncthreads();
        for (int n = 0; n < 32; ++n) {
            const float* kr = kl + n * 128 + ty * 8;
            const float* vr = vl + n * 128 + tx * 8;
            float4 ka = *(const float4*)(kr),  kb4 = *(const float4*)(kr + 4);
            float4 va = *(const float4*)(vr),  vb4 = *(const float4*)(vr + 4);
            float av[8]  = {ka.x,ka.y,ka.z,ka.w,kb4.x,kb4.y,kb4.z,kb4.w};
            float bvv[8] = {va.x,va.y,va.z,va.w,vb4.x,vb4.y,vb4.z,vb4.w};
#pragma unroll
            for (int i = 0; i < 8; ++i)
#pragma unroll
                for (int j = 0; j < 8; ++j) acc[i][j] += av[i] * bvv[j];
        }
    }
    size_t sbase = ((size_t)(b * 16 + ns)) << 14;
#pragma unroll
    for (int i = 0; i < 8; ++i) {
        int cp = ty * 8 + i;
        *(float4*)(sp + sbase + (cp << 7) + tx * 8)     = make_float4(acc[i][0], acc[i][1], acc[i][2], acc[i][3]);
        *(float4*)(sp + sbase + (cp << 7) + tx * 8 + 4) = make_float4(acc[i][4], acc[i][5], acc[i][6], acc[i][7]);
    }
}

// ---------------- K4b: reduce 16 partials -> S_pad[b][122][128] ----------------
__global__ __launch_bounds__(256) void k4b_reduce(const float* __restrict__ sp, float* __restrict__ spad) {
    int idx = blockIdx.x * 256 + threadIdx.x;
    if (idx >= 32 * 122 * 128) return;
    int c = idx & 127;
    int r = (idx >> 7) % 122;
    int b = idx / (122 * 128);
    float s = 0.f;
    if (c < 122) {
        const float* p = sp + (((size_t)b * 16) << 14) + (r << 7) + c;
#pragma unroll
        for (int q = 0; q < 16; ++q) s += p[(size_t)q << 14];
    }
    spad[idx] = s;
}

// ---------------- K4c: fold f_w (and BN scale) into S: Tt[b][122][64] ----------------
// Tt[cp][o] = fg[o]/sqrt(fv[o]+eps) * sum_c fw[o][c] * S[cp][c]
__global__ __launch_bounds__(256) void k4c_fold(
    const float* __restrict__ spad, const float* __restrict__ fw,
    const float* __restrict__ fg, const float* __restrict__ fv,
    float* __restrict__ Tt) {
    __shared__ __align__(16) float sl[122 * 128];   // 62.5 KB, 1 block/CU, 32 blocks
    int b = blockIdx.x, tid = threadIdx.x;
    for (int i = tid; i < 3904; i += 256)
        *(float4*)(sl + i * 4) = *(const float4*)(spad + (size_t)b * 15616 + i * 4);
    __syncthreads();
    int o = tid & 63, cpg = tid >> 6;
    if (o < 61) {
        float sc = fg[o] * rsqrtf(fv[o] + EPS);
        const float* fwr = fw + o * 122;
        for (int cp = cpg; cp < 122; cp += 4) {
            const float* sr = sl + cp * 128;
            float s = 0.f;
            for (int c = 0; c < 122; ++c) s += fwr[c] * sr[c];
            Tt[((size_t)b * 122 + cp) * 64 + o] = sc * s;
        }
    }
}

// ---------------- K5: NT=16 tail: fused = relu(T q + sh) ; c1 ; c2 ; c3 ----------------
// grid (64 ntiles, 32 b); thread = (nq 0..3, og 0..63). P2 (val) eliminated by
// the k4c T-fold. LDS overlay 7560 floats (30.2 KB -> 5 blocks/CU):
// QT[122][20]@0 -> FUS[61][16]@0 ; H1[256][16]@2440 ; H2[64][16]@6536.
__global__ __launch_bounds__(256) void k5_tail(
    const float* __restrict__ qbuf, const float* __restrict__ Tt,
    const float* __restrict__ fg, const float* __restrict__ fbb,
    const float* __restrict__ fm, const float* __restrict__ fv,
    const float* __restrict__ w1, const float* __restrict__ bb1,
    const float* __restrict__ w2, const float* __restrict__ bb2,
    const float* __restrict__ w3, const float* __restrict__ bb3,
    float* __restrict__ out) {
    __shared__ __align__(16) float lds[7560];
    const int FUS = 0, H1 = 2440, H2 = 6536;
    int tid = threadIdx.x;
    int b = blockIdx.y;
    int n0 = blockIdx.x << 4;
    int nq = tid & 3, og = tid >> 2;
    // stage QT[cp][n] transposed from qbuf[b][n][128]
    for (int i = tid; i < 512; i += 256) {
        int n = i >> 5, c4 = i & 31;
        float4 x = *(const float4*)(qbuf + ((size_t)b * 1024 + n0 + n) * 128 + c4 * 4);
        lds[(c4*4+0)*20 + n] = x.x;
        lds[(c4*4+1)*20 + n] = x.y;
        lds[(c4*4+2)*20 + n] = x.z;
        lds[(c4*4+3)*20 + n] = x.w;
    }
    __syncthreads();
    {   // P2': fused[og][n] = relu( sum_cp Tt[cp][og] * q[cp][n] + sh[og] ), og<61
        float4 y = make_float4(0.f, 0.f, 0.f, 0.f);
        const bool act = (og < 61);
        if (act) {
            float4 a0 = make_float4(0,0,0,0);
            const float* tb = Tt + (size_t)b * 7808 + og;   // 122*64
            for (int cp = 0; cp < 122; ++cp) {
                float4 tv = *(const float4*)(lds + cp * 20 + nq * 4);
                FMA4(a0, tb[cp << 6], tv);
            }
            float sc = fg[og] * rsqrtf(fv[og] + EPS);
            float sh = fbb[og] - fm[og] * sc;      // scale already folded into Tt
            y.x = fmaxf(a0.x + sh, 0.f); y.y = fmaxf(a0.y + sh, 0.f);
            y.z = fmaxf(a0.z + sh, 0.f); y.w = fmaxf(a0.w + sh, 0.f);
        }
        __syncthreads();   // all QT reads done (FUS overwrites region 0)
        if (act) *(float4*)(lds + FUS + og*16 + nq*4) = y;
        __syncthreads();
    }
    {   // P4: h1[o][n] = relu(c1_w @ fused + c1_b), o = og + 64*i -> H1 (disjoint)
        float4 a[4];
#pragma unroll
        for (int i = 0; i < 4; ++i) a[i] = make_float4(0,0,0,0);
        for (int c = 0; c < 61; ++c) {
            float4 tv = *(const float4*)(lds + FUS + c*16 + nq*4);
#pragma unroll
            for (int i = 0; i < 4; ++i) {
                float w = w1[(og + (i<<6)) * 61 + c];
                FMA4(a[i], w, tv);
            }
        }
#pragma unroll
        for (int i = 0; i < 4; ++i) {
            int o = og + (i<<6);
            float bias = bb1[o];
            float4 y;
            y.x = fmaxf(a[i].x + bias, 0.f); y.y = fmaxf(a[i].y + bias, 0.f);
            y.z = fmaxf(a[i].z + bias, 0.f); y.w = fmaxf(a[i].w + bias, 0.f);
            *(float4*)(lds + H1 + o*16 + nq*4) = y;
        }
        __syncthreads();
    }
    {   // P5: h2[o][n] = relu(c2_w @ h1 + c2_b), o = og -> H2 (disjoint)
        float4 a0 = make_float4(0,0,0,0);
        const float* w2r = w2 + og * 256;
        for (int c = 0; c < 256; ++c) {
            float4 tv = *(const float4*)(lds + H1 + c*16 + nq*4);
            FMA4(a0, w2r[c], tv);
        }
        float ba = bb2[og];
        float4 y;
        y.x = fmaxf(a0.x + ba, 0.f); y.y = fmaxf(a0.y + ba, 0.f);
        y.z = fmaxf(a0.z + ba, 0.f); y.w = fmaxf(a0.w + ba, 0.f);
        *(float4*)(lds + H2 + og*16 + nq*4) = y;
        __syncthreads();
    }
    if (og < 3) {   // P6: sigmoid - 0.5, transposed FP32 store
        float4 a = make_float4(0,0,0,0);
        const float* w3r = w3 + og * 64;
        for (int c = 0; c < 64; ++c) {
            float4 tv = *(const float4*)(lds + H2 + c*16 + nq*4);
            FMA4(a, w3r[c], tv);
        }
        float bias = bb3[og];
        int nbase = n0 + nq*4;
        out[((size_t)b*1024 + nbase + 0)*3 + og] = 1.f/(1.f+expf(-(a.x+bias))) - 0.5f;
        out[((size_t)b*1024 + nbase + 1)*3 + og] = 1.f/(1.f+expf(-(a.y+bias))) - 0.5f;
        out[((size_t)b*1024 + nbase + 2)*3 + og] = 1.f/(1.f+expf(-(a.z+bias))) - 0.5f;
        out[((size_t)b*1024 + nbase + 3)*3 + og] = 1.f/(1.f+expf(-(a.w+bias))) - 0.5f;
    }
}

extern "C" void kernel_launch(void* const* d_in, const int* in_sizes, int n_in,
                              void* d_out, int out_size, void* d_ws, size_t ws_size,
                              hipStream_t stream) {
    const float* gf      = (const float*)d_in[0];
    const float* token_w = (const float*)d_in[3];
    const float* token_b = (const float*)d_in[4];
    const float* tbn_g   = (const float*)d_in[5];
    const float* tbn_b   = (const float*)d_in[6];
    const float* tbn_m   = (const float*)d_in[7];
    const float* tbn_v   = (const float*)d_in[8];
    const float* q_w = (const float*)d_in[9];
    const float* qg  = (const float*)d_in[10];
    const float* qb  = (const float*)d_in[11];
    const float* qm  = (const float*)d_in[12];
    const float* qv  = (const float*)d_in[13];
    const float* k_w = (const float*)d_in[14];
    const float* kg  = (const float*)d_in[15];
    const float* kb  = (const float*)d_in[16];
    const float* km  = (const float*)d_in[17];
    const float* kv  = (const float*)d_in[18];
    const float* v_w = (const float*)d_in[19];
    const float* vg  = (const float*)d_in[20];
    const float* vb  = (const float*)d_in[21];
    const float* vm  = (const float*)d_in[22];
    const float* vv  = (const float*)d_in[23];
    const float* f_w = (const float*)d_in[24];
    const float* fg  = (const float*)d_in[25];
    const float* fb  = (const float*)d_in[26];
    const float* fm  = (const float*)d_in[27];
    const float* fv  = (const float*)d_in[28];
    const float* c1w = (const float*)d_in[29];
    const float* c1b = (const float*)d_in[30];
    const float* c2w = (const float*)d_in[31];
    const float* c2b = (const float*)d_in[32];
    const float* c3w = (const float*)d_in[33];
    const float* c3b = (const float*)d_in[34];

    float* ws    = (float*)d_ws;
    float* gfeat = ws;                       // 16,384
    float* tok   = gfeat + 16384;            // 2,097,152
    float* kbuf  = tok   + 2097152;          // 4,194,304
    float* vbuf  = kbuf  + 4194304;          // 4,194,304
    float* qbuf  = vbuf  + 4194304;          // 4,194,304
    float* sp    = qbuf  + 4194304;          // 8,388,608
    float* spad  = sp    + 8388608;          // 499,712
    float* Tt    = spad  + 499712;           // 32*122*64 = 249,856  -> ~97 MB total

    k1_maxpool<<<4096, 256, 0, stream>>>(gf, gfeat);
    k2_token  <<<512, 256, 0, stream>>>(gfeat, token_w, token_b, tbn_g, tbn_b, tbn_m, tbn_v, tok);
    k3_kv     <<<dim3(16, 32), 256, 0, stream>>>(tok, k_w, v_w,
                 kg, kb, km, kv, vg, vb, vm, vv, kbuf, vbuf);
    k3_q      <<<dim3(16, 32), 256, 0, stream>>>(tok, q_w, qg, qb, qm, qv, qbuf);
    k4_s      <<<dim3(16, 32), 256, 0, stream>>>(kbuf, vbuf, sp);
    k4b_reduce<<<1952, 256, 0, stream>>>(sp, spad);
    k4c_fold  <<<32, 256, 0, stream>>>(spad, f_w, fg, fv, Tt);
    k5_tail   <<<dim3(64, 32), 256, 0, stream>>>(qbuf, Tt,
                 fg, fb, fm, fv, c1w, c1b, c2w, c2b, c3w, c3b, (float*)d_out);
}

// Round 14
// 275.122 us; speedup vs baseline: 1.1132x; 1.1132x over previous
//
#include <hip/hip_runtime.h>
#include <float.h>

#define EPS 1e-5f
#define FMA4(A_, W_, T_) { (A_).x += (W_)*(T_).x; (A_).y += (W_)*(T_).y; (A_).z += (W_)*(T_).z; (A_).w += (W_)*(T_).w; }

// ---------------- K0: pad w1 (256x61) -> w1p (256x64, zero-padded cols) ----------------
__global__ __launch_bounds__(256) void k0_prep(const float* __restrict__ w1, float* __restrict__ w1p) {
    int i = blockIdx.x * 256 + threadIdx.x;
    if (i < 16384) {
        int o = i >> 6, c = i & 63;
        w1p[i] = (c < 61) ? w1[o * 61 + c] : 0.f;
    }
}

// ---------------- K1: max over last dim: (32,512,2048) -> (32*512) ----------------
__global__ __launch_bounds__(256) void k1_maxpool(const float* __restrict__ gf, float* __restrict__ gfeat) {
    int row = blockIdx.x * 4 + (threadIdx.x >> 6);   // one wave per row
    int lane = threadIdx.x & 63;
    const float4* p = (const float4*)(gf + (size_t)row * 2048);
    float m = -FLT_MAX;
#pragma unroll
    for (int w = 0; w < 8; ++w) {
        float4 v = p[lane + (w << 6)];
        m = fmaxf(m, fmaxf(fmaxf(v.x, v.y), fmaxf(v.z, v.w)));
    }
#pragma unroll
    for (int off = 32; off >= 1; off >>= 1) m = fmaxf(m, __shfl_xor(m, off));
    if (lane == 0) gfeat[row] = m;
}

// ---------------- K2: tok = relu(bn(gfeat @ token_w^T + token_b)) : (32,65536) ----------------
__global__ __launch_bounds__(256) void k2_token(
    const float* __restrict__ gfeat, const float* __restrict__ tw, const float* __restrict__ tbias,
    const float* __restrict__ bg, const float* __restrict__ bb,
    const float* __restrict__ bm, const float* __restrict__ bv,
    float* __restrict__ tok) {
    __shared__ __align__(16) float wl[128 * 33];
    __shared__ __align__(16) float gl[32 * 36];
    int tid = threadIdx.x;
    int t0 = blockIdx.x * 128;
    int tx = tid & 7, ty = tid >> 3;
    float4 acc[4];
#pragma unroll
    for (int i = 0; i < 4; ++i) acc[i] = make_float4(0.f, 0.f, 0.f, 0.f);
    for (int k0 = 0; k0 < 512; k0 += 32) {
        if (k0) __syncthreads();
        {
            int r = tid >> 1, h = tid & 1;
            const float* src = tw + (size_t)(t0 + r) * 512 + k0 + h * 16;
            float* dst = wl + r * 33 + h * 16;
#pragma unroll
            for (int q = 0; q < 4; ++q) {
                float4 x = *(const float4*)(src + q * 4);
                dst[q*4+0] = x.x; dst[q*4+1] = x.y; dst[q*4+2] = x.z; dst[q*4+3] = x.w;
            }
            int bq = tid >> 3, kq = tid & 7;
            float4 gx = *(const float4*)(gfeat + bq * 512 + k0 + kq * 4);
            gl[(kq*4+0)*36 + bq] = gx.x;
            gl[(kq*4+1)*36 + bq] = gx.y;
            gl[(kq*4+2)*36 + bq] = gx.z;
            gl[(kq*4+3)*36 + bq] = gx.w;
        }
        __syncthreads();
#pragma unroll
        for (int kk = 0; kk < 32; ++kk) {
            float4 g4 = *(const float4*)(gl + kk * 36 + tx * 4);
#pragma unroll
            for (int i = 0; i < 4; ++i) {
                float a = wl[(ty * 4 + i) * 33 + kk];
                FMA4(acc[i], a, g4);
            }
        }
    }
#pragma unroll
    for (int i = 0; i < 4; ++i) {
        int t = t0 + ty * 4 + i;
        float scale = bg[t] * rsqrtf(bv[t] + EPS);
        float sh = (tbias[t] - bm[t]) * scale + bb[t];
        tok[(size_t)(tx*4+0) * 65536 + t] = fmaxf(acc[i].x * scale + sh, 0.f);
        tok[(size_t)(tx*4+1) * 65536 + t] = fmaxf(acc[i].y * scale + sh, 0.f);
        tok[(size_t)(tx*4+2) * 65536 + t] = fmaxf(acc[i].z * scale + sh, 0.f);
        tok[(size_t)(tx*4+3) * 65536 + t] = fmaxf(acc[i].w * scale + sh, 0.f);
    }
}

// ---------------- K3: k,v projections -> padded [b][n][128] buffers ----------------
__global__ __launch_bounds__(256) void k3_kv(
    const float* __restrict__ tok,
    const float* __restrict__ kw, const float* __restrict__ vw,
    const float* __restrict__ kg, const float* __restrict__ kb, const float* __restrict__ km, const float* __restrict__ kvv,
    const float* __restrict__ vg, const float* __restrict__ vb, const float* __restrict__ vm, const float* __restrict__ vvv,
    float* __restrict__ kbuf, float* __restrict__ vbuf) {
    __shared__ __align__(16) float tokt[64 * 68];    // [n][c]
    int tid = threadIdx.x;
    int b = blockIdx.y;
    int n0 = blockIdx.x << 6;
    for (int i = tid; i < 1024; i += 256) {
        int c = i >> 4, q4 = i & 15;
        float4 x = *(const float4*)(tok + (size_t)b * 65536 + c * 1024 + n0 + q4 * 4);
        tokt[(q4*4+0)*68 + c] = x.x;
        tokt[(q4*4+1)*68 + c] = x.y;
        tokt[(q4*4+2)*68 + c] = x.z;
        tokt[(q4*4+3)*68 + c] = x.w;
    }
    int o = tid & 127;
    bool valid = (o < 122);
    float kscl = 0.f, kshf = 0.f, vscl = 0.f, vshf = 0.f;
    if (valid) {
        float s = kg[o] * rsqrtf(kvv[o] + EPS);
        kscl = s; kshf = kb[o] - km[o] * s;
        s = vg[o] * rsqrtf(vvv[o] + EPS);
        vscl = s; vshf = vb[o] - vm[o] * s;
    }
    float4 kwreg[16], vwreg[16];
    {
        const float* kwr = kw + o * 64;
        const float* vwr = vw + o * 64;
#pragma unroll
        for (int c4 = 0; c4 < 16; ++c4) {
            kwreg[c4] = valid ? *(const float4*)(kwr + c4 * 4) : make_float4(0.f,0.f,0.f,0.f);
            vwreg[c4] = valid ? *(const float4*)(vwr + c4 * 4) : make_float4(0.f,0.f,0.f,0.f);
        }
    }
    __syncthreads();
    for (int nn = (tid >> 7); nn < 64; nn += 2) {
        const float* t = tokt + nn * 68;
        float sk = 0.f, sv = 0.f;
#pragma unroll
        for (int c4 = 0; c4 < 16; ++c4) {
            float4 tv = *(const float4*)(t + c4 * 4);
            sk += kwreg[c4].x*tv.x + kwreg[c4].y*tv.y + kwreg[c4].z*tv.z + kwreg[c4].w*tv.w;
            sv += vwreg[c4].x*tv.x + vwreg[c4].y*tv.y + vwreg[c4].z*tv.z + vwreg[c4].w*tv.w;
        }
        size_t base = ((size_t)b * 1024 + n0 + nn) * 128 + o;
        kbuf[base] = fmaxf(sk * kscl + kshf, 0.f);
        vbuf[base] = fmaxf(sv * vscl + vshf, 0.f);
    }
}

// ---------------- K3q: q projection -> padded [b][n][128] ----------------
__global__ __launch_bounds__(256) void k3_q(
    const float* __restrict__ tok,
    const float* __restrict__ qw,
    const float* __restrict__ qg, const float* __restrict__ qb, const float* __restrict__ qm, const float* __restrict__ qv,
    float* __restrict__ qbuf) {
    __shared__ __align__(16) float tokt[64 * 68];
    int tid = threadIdx.x;
    int b = blockIdx.y;
    int n0 = blockIdx.x << 6;
    for (int i = tid; i < 1024; i += 256) {
        int c = i >> 4, q4 = i & 15;
        float4 x = *(const float4*)(tok + (size_t)b * 65536 + c * 1024 + n0 + q4 * 4);
        tokt[(q4*4+0)*68 + c] = x.x;
        tokt[(q4*4+1)*68 + c] = x.y;
        tokt[(q4*4+2)*68 + c] = x.z;
        tokt[(q4*4+3)*68 + c] = x.w;
    }
    int o = tid & 127;
    bool valid = (o < 122);
    float scl = 0.f, shf = 0.f;
    if (valid) {
        float s = qg[o] * rsqrtf(qv[o] + EPS);
        scl = s; shf = qb[o] - qm[o] * s;
    }
    float4 wreg[16];
    {
        const float* wr = qw + o * 64;
#pragma unroll
        for (int c4 = 0; c4 < 16; ++c4)
            wreg[c4] = valid ? *(const float4*)(wr + c4 * 4) : make_float4(0.f,0.f,0.f,0.f);
    }
    __syncthreads();
    for (int nn = (tid >> 7); nn < 64; nn += 2) {
        const float* t = tokt + nn * 68;
        float s = 0.f;
#pragma unroll
        for (int c4 = 0; c4 < 16; ++c4) {
            float4 tv = *(const float4*)(t + c4 * 4);
            s += wreg[c4].x*tv.x + wreg[c4].y*tv.y + wreg[c4].z*tv.z + wreg[c4].w*tv.w;
        }
        qbuf[((size_t)b * 1024 + n0 + nn) * 128 + o] = fmaxf(s * scl + shf, 0.f);
    }
}

// ---------------- K4: S partials — pure outer-product GEMM over n ----------------
__global__ __launch_bounds__(256) void k4_s(
    const float* __restrict__ kbuf, const float* __restrict__ vbuf,
    float* __restrict__ sp) {
    __shared__ __align__(16) float kl[32 * 128];
    __shared__ __align__(16) float vl[32 * 128];
    int tid = threadIdx.x;
    int b = blockIdx.y, ns = blockIdx.x;
    int tx = tid & 15, ty = tid >> 4;
    float acc[8][8];
#pragma unroll
    for (int i = 0; i < 8; ++i)
#pragma unroll
        for (int j = 0; j < 8; ++j) acc[i][j] = 0.f;
    for (int chunk = 0; chunk < 2; ++chunk) {
        int nb = (ns << 6) + (chunk << 5);
        if (chunk) __syncthreads();
        for (int i = tid; i < 1024; i += 256) {
            int n = i >> 5, q = i & 31;
            size_t src = ((size_t)b * 1024 + nb + n) * 128 + q * 4;
            *(float4*)(kl + n * 128 + q * 4) = *(const float4*)(kbuf + src);
            *(float4*)(vl + n * 128 + q * 4) = *(const float4*)(vbuf + src);
        }
        __syncthreads();
        for (int n = 0; n < 32; ++n) {
            const float* kr = kl + n * 128 + ty * 8;
            const float* vr = vl + n * 128 + tx * 8;
            float4 ka = *(const float4*)(kr),  kb4 = *(const float4*)(kr + 4);
            float4 va = *(const float4*)(vr),  vb4 = *(const float4*)(vr + 4);
            float av[8]  = {ka.x,ka.y,ka.z,ka.w,kb4.x,kb4.y,kb4.z,kb4.w};
            float bvv[8] = {va.x,va.y,va.z,va.w,vb4.x,vb4.y,vb4.z,vb4.w};
#pragma unroll
            for (int i = 0; i < 8; ++i)
#pragma unroll
                for (int j = 0; j < 8; ++j) acc[i][j] += av[i] * bvv[j];
        }
    }
    size_t sbase = ((size_t)(b * 16 + ns)) << 14;
#pragma unroll
    for (int i = 0; i < 8; ++i) {
        int cp = ty * 8 + i;
        *(float4*)(sp + sbase + (cp << 7) + tx * 8)     = make_float4(acc[i][0], acc[i][1], acc[i][2], acc[i][3]);
        *(float4*)(sp + sbase + (cp << 7) + tx * 8 + 4) = make_float4(acc[i][4], acc[i][5], acc[i][6], acc[i][7]);
    }
}

// ---------------- K4bc: reduce 16 partials + fold f_w/BN-scale -> Tt[b][122][64] ----------------
// grid (4 cp-groups, 32 b). Tt[cp][o] = fg[o]*rsqrt(fv[o]+eps) * sum_c fw[o][c]*S[cp][c]
__global__ __launch_bounds__(256) void k4bc_fold(
    const float* __restrict__ sp, const float* __restrict__ fw,
    const float* __restrict__ fg, const float* __restrict__ fv,
    float* __restrict__ Tt) {
    __shared__ __align__(16) float sl[32 * 128];   // 16 KB: S rows cp0..cp0+31
    int b = blockIdx.y, g = blockIdx.x;
    int tid = threadIdx.x;
    int cp0 = g << 5;
    for (int i = tid; i < 1024; i += 256) {        // 32*128 floats / 4
        const float* p = sp + (((size_t)b * 16) << 14) + (size_t)cp0 * 128 + i * 4;
        float4 acc = make_float4(0.f, 0.f, 0.f, 0.f);
#pragma unroll
        for (int q = 0; q < 16; ++q) {
            float4 x = *(const float4*)(p + ((size_t)q << 14));
            acc.x += x.x; acc.y += x.y; acc.z += x.z; acc.w += x.w;
        }
        *(float4*)(sl + i * 4) = acc;
    }
    __syncthreads();
    int o = tid & 63, cpg = tid >> 6;
    if (o < 61) {
        float sc = fg[o] * rsqrtf(fv[o] + EPS);
        const float* fwr = fw + o * 122;
        for (int k = cpg; k < 32; k += 4) {
            int cp = cp0 + k;
            if (cp >= 122) break;
            const float* sr = sl + k * 128;
            float s = 0.f;
            for (int c = 0; c < 122; ++c) s += fwr[c] * sr[c];
            Tt[((size_t)b * 122 + cp) * 64 + o] = sc * s;
        }
    }
}

// ---------------- K5: NT=16 tail: fused = relu(T q + sh) ; c1 ; c2 ; c3 ----------------
// grid (64 ntiles, 32 b); thread = (nq 0..3, og 0..63). Weights streamed as float4
// (w1 padded to [256][64] by k0_prep; w2/w3 naturally aligned). LDS 24.6 KB ->
// 6 blocks/CU. Overlay: QT[122][20]@0 -> FUS[64][16]@0 ; H1[256][16]@1024 ;
// H2[64][16]@5120. All barriers uniform.
__global__ __launch_bounds__(256) void k5_tail(
    const float* __restrict__ qbuf, const float* __restrict__ Tt,
    const float* __restrict__ fg, const float* __restrict__ fbb,
    const float* __restrict__ fm, const float* __restrict__ fv,
    const float* __restrict__ w1p, const float* __restrict__ bb1,
    const float* __restrict__ w2, const float* __restrict__ bb2,
    const float* __restrict__ w3, const float* __restrict__ bb3,
    float* __restrict__ out) {
    __shared__ __align__(16) float lds[6144];
    const int FUS = 0, H1 = 1024, H2 = 5120;
    int tid = threadIdx.x;
    int b = blockIdx.y;
    int n0 = blockIdx.x << 4;
    int nq = tid & 3, og = tid >> 2;
    // stage QT[cp][n] transposed from qbuf[b][n][128]
    for (int i = tid; i < 512; i += 256) {
        int n = i >> 5, c4 = i & 31;
        float4 x = *(const float4*)(qbuf + ((size_t)b * 1024 + n0 + n) * 128 + c4 * 4);
        lds[(c4*4+0)*20 + n] = x.x;
        lds[(c4*4+1)*20 + n] = x.y;
        lds[(c4*4+2)*20 + n] = x.z;
        lds[(c4*4+3)*20 + n] = x.w;
    }
    __syncthreads();
    {   // P2': fused[og][n] = relu( sum_cp Tt[cp][og] * q[cp][n] + sh[og] ), og<61
        float4 y = make_float4(0.f, 0.f, 0.f, 0.f);
        const bool act = (og < 61);
        if (act) {
            float4 a0 = make_float4(0,0,0,0);
            const float* tb = Tt + (size_t)b * 7808 + og;   // 122*64
            for (int cp = 0; cp < 122; ++cp) {
                float4 tv = *(const float4*)(lds + cp * 20 + nq * 4);
                FMA4(a0, tb[cp << 6], tv);
            }
            float sc = fg[og] * rsqrtf(fv[og] + EPS);
            float sh = fbb[og] - fm[og] * sc;      // scale already folded into Tt
            y.x = fmaxf(a0.x + sh, 0.f); y.y = fmaxf(a0.y + sh, 0.f);
            y.z = fmaxf(a0.z + sh, 0.f); y.w = fmaxf(a0.w + sh, 0.f);
        }
        __syncthreads();   // all QT reads done (FUS overwrites region 0)
        if (og < 61) *(float4*)(lds + FUS + og*16 + nq*4) = y;
        if (og >= 61 && og < 64) {   // zero pad rows 61..63 (read by P4 with w=0 anyway)
            *(float4*)(lds + FUS + og*16 + nq*4) = make_float4(0.f,0.f,0.f,0.f);
        }
        __syncthreads();
    }
    {   // P4: h1[o][n] = relu(c1_w @ fused + c1_b), o = og + 64*i -> H1 (disjoint)
        float4 a[4];
#pragma unroll
        for (int i = 0; i < 4; ++i) a[i] = make_float4(0,0,0,0);
#pragma unroll
        for (int c4 = 0; c4 < 16; ++c4) {
            float4 t0 = *(const float4*)(lds + FUS + (c4*4+0)*16 + nq*4);
            float4 t1 = *(const float4*)(lds + FUS + (c4*4+1)*16 + nq*4);
            float4 t2 = *(const float4*)(lds + FUS + (c4*4+2)*16 + nq*4);
            float4 t3 = *(const float4*)(lds + FUS + (c4*4+3)*16 + nq*4);
#pragma unroll
            for (int i = 0; i < 4; ++i) {
                float4 w = *(const float4*)(w1p + (og + (i<<6)) * 64 + c4 * 4);
                FMA4(a[i], w.x, t0);
                FMA4(a[i], w.y, t1);
                FMA4(a[i], w.z, t2);
                FMA4(a[i], w.w, t3);
            }
        }
#pragma unroll
        for (int i = 0; i < 4; ++i) {
            int o = og + (i<<6);
            float bias = bb1[o];
            float4 y;
            y.x = fmaxf(a[i].x + bias, 0.f); y.y = fmaxf(a[i].y + bias, 0.f);
            y.z = fmaxf(a[i].z + bias, 0.f); y.w = fmaxf(a[i].w + bias, 0.f);
            *(float4*)(lds + H1 + o*16 + nq*4) = y;
        }
        __syncthreads();
    }
    {   // P5: h2[o][n] = relu(c2_w @ h1 + c2_b), o = og -> H2 (disjoint)
        float4 a0 = make_float4(0,0,0,0);
        const float* w2r = w2 + og * 256;
#pragma unroll 8
        for (int c4 = 0; c4 < 64; ++c4) {
            float4 w  = *(const float4*)(w2r + c4 * 4);
            float4 t0 = *(const float4*)(lds + H1 + (c4*4+0)*16 + nq*4);
            float4 t1 = *(const float4*)(lds + H1 + (c4*4+1)*16 + nq*4);
            float4 t2 = *(const float4*)(lds + H1 + (c4*4+2)*16 + nq*4);
            float4 t3 = *(const float4*)(lds + H1 + (c4*4+3)*16 + nq*4);
            FMA4(a0, w.x, t0);
            FMA4(a0, w.y, t1);
            FMA4(a0, w.z, t2);
            FMA4(a0, w.w, t3);
        }
        float ba = bb2[og];
        float4 y;
        y.x = fmaxf(a0.x + ba, 0.f); y.y = fmaxf(a0.y + ba, 0.f);
        y.z = fmaxf(a0.z + ba, 0.f); y.w = fmaxf(a0.w + ba, 0.f);
        *(float4*)(lds + H2 + og*16 + nq*4) = y;
        __syncthreads();
    }
    if (og < 3) {   // P6: sigmoid - 0.5, transposed FP32 store
        float4 a = make_float4(0,0,0,0);
        const float* w3r = w3 + og * 64;
#pragma unroll
        for (int c4 = 0; c4 < 16; ++c4) {
            float4 w  = *(const float4*)(w3r + c4 * 4);
            float4 t0 = *(const float4*)(lds + H2 + (c4*4+0)*16 + nq*4);
            float4 t1 = *(const float4*)(lds + H2 + (c4*4+1)*16 + nq*4);
            float4 t2 = *(const float4*)(lds + H2 + (c4*4+2)*16 + nq*4);
            float4 t3 = *(const float4*)(lds + H2 + (c4*4+3)*16 + nq*4);
            FMA4(a, w.x, t0);
            FMA4(a, w.y, t1);
            FMA4(a, w.z, t2);
            FMA4(a, w.w, t3);
        }
        float bias = bb3[og];
        int nbase = n0 + nq*4;
        out[((size_t)b*1024 + nbase + 0)*3 + og] = 1.f/(1.f+expf(-(a.x+bias))) - 0.5f;
        out[((size_t)b*1024 + nbase + 1)*3 + og] = 1.f/(1.f+expf(-(a.y+bias))) - 0.5f;
        out[((size_t)b*1024 + nbase + 2)*3 + og] = 1.f/(1.f+expf(-(a.z+bias))) - 0.5f;
        out[((size_t)b*1024 + nbase + 3)*3 + og] = 1.f/(1.f+expf(-(a.w+bias))) - 0.5f;
    }
}

extern "C" void kernel_launch(void* const* d_in, const int* in_sizes, int n_in,
                              void* d_out, int out_size, void* d_ws, size_t ws_size,
                              hipStream_t stream) {
    const float* gf      = (const float*)d_in[0];
    const float* token_w = (const float*)d_in[3];
    const float* token_b = (const float*)d_in[4];
    const float* tbn_g   = (const float*)d_in[5];
    const float* tbn_b   = (const float*)d_in[6];
    const float* tbn_m   = (const float*)d_in[7];
    const float* tbn_v   = (const float*)d_in[8];
    const float* q_w = (const float*)d_in[9];
    const float* qg  = (const float*)d_in[10];
    const float* qb  = (const float*)d_in[11];
    const float* qm  = (const float*)d_in[12];
    const float* qv  = (const float*)d_in[13];
    const float* k_w = (const float*)d_in[14];
    const float* kg  = (const float*)d_in[15];
    const float* kb  = (const float*)d_in[16];
    const float* km  = (const float*)d_in[17];
    const float* kv  = (const float*)d_in[18];
    const float* v_w = (const float*)d_in[19];
    const float* vg  = (const float*)d_in[20];
    const float* vb  = (const float*)d_in[21];
    const float* vm  = (const float*)d_in[22];
    const float* vv  = (const float*)d_in[23];
    const float* f_w = (const float*)d_in[24];
    const float* fg  = (const float*)d_in[25];
    const float* fb  = (const float*)d_in[26];
    const float* fm  = (const float*)d_in[27];
    const float* fv  = (const float*)d_in[28];
    const float* c1w = (const float*)d_in[29];
    const float* c1b = (const float*)d_in[30];
    const float* c2w = (const float*)d_in[31];
    const float* c2b = (const float*)d_in[32];
    const float* c3w = (const float*)d_in[33];
    const float* c3b = (const float*)d_in[34];

    float* ws    = (float*)d_ws;
    float* gfeat = ws;                       // 16,384
    float* tok   = gfeat + 16384;            // 2,097,152
    float* kbuf  = tok   + 2097152;          // 4,194,304
    float* vbuf  = kbuf  + 4194304;          // 4,194,304
    float* qbuf  = vbuf  + 4194304;          // 4,194,304
    float* sp    = qbuf  + 4194304;          // 8,388,608
    float* Tt    = sp    + 8388608;          // 249,856
    float* w1p   = Tt    + 249856;           // 16,384   -> ~93.4 MB total

    k0_prep   <<<64, 256, 0, stream>>>(c1w, w1p);
    k1_maxpool<<<4096, 256, 0, stream>>>(gf, gfeat);
    k2_token  <<<512, 256, 0, stream>>>(gfeat, token_w, token_b, tbn_g, tbn_b, tbn_m, tbn_v, tok);
    k3_kv     <<<dim3(16, 32), 256, 0, stream>>>(tok, k_w, v_w,
                 kg, kb, km, kv, vg, vb, vm, vv, kbuf, vbuf);
    k3_q      <<<dim3(16, 32), 256, 0, stream>>>(tok, q_w, qg, qb, qm, qv, qbuf);
    k4_s      <<<dim3(16, 32), 256, 0, stream>>>(kbuf, vbuf, sp);
    k4bc_fold <<<dim3(4, 32), 256, 0, stream>>>(sp, f_w, fg, fv, Tt);
    k5_tail   <<<dim3(64, 32), 256, 0, stream>>>(qbuf, Tt,
                 fg, fb, fm, fv, w1p, c1b, c2w, c2b, c3w, c3b, (float*)d_out);
}